// Round 2
// baseline (1669.838 us; speedup 1.0000x reference)
//
#include <hip/hip_runtime.h>
#include <hip/hip_bf16.h>

#define N_NODES 50000
#define N_EDGES 800000
#define DIM_D 128
#define DIM_H 256
#define DIM_P 512
#define DIM_O 64

typedef unsigned short bf16r;  // raw bf16 bits

__device__ __forceinline__ float b2f(bf16r s) {
  unsigned int u = ((unsigned int)s) << 16;
  float f;
  __builtin_memcpy(&f, &u, 4);
  return f;
}
__device__ __forceinline__ bf16r f2b(float f) {
  unsigned int u;
  __builtin_memcpy(&u, &f, 4);
  u += 0x7fffu + ((u >> 16) & 1u);  // round-to-nearest-even
  return (bf16r)(u >> 16);
}

__device__ __forceinline__ float4 ld4(const float* p) {
  return *reinterpret_cast<const float4*>(p);
}
__device__ __forceinline__ float4 ld4(const bf16r* p) {
  ushort4 u = *reinterpret_cast<const ushort4*>(p);
  return make_float4(b2f(u.x), b2f(u.y), b2f(u.z), b2f(u.w));
}
__device__ __forceinline__ void st4(float* p, float4 v) {
  *reinterpret_cast<float4*>(p) = v;
}
__device__ __forceinline__ void st4(bf16r* p, float4 v) {
  ushort4 u;
  u.x = f2b(v.x); u.y = f2b(v.y); u.z = f2b(v.z); u.w = f2b(v.w);
  *reinterpret_cast<ushort4*>(p) = u;
}

// ---------------- small utility ----------------
__global__ void zero_ints(int* __restrict__ p, int n) {
  int i = blockIdx.x * blockDim.x + threadIdx.x;
  if (i < n) p[i] = 0;
}

// ---------------- CSR build (by dst) ----------------
__global__ void count_edges(const int* __restrict__ dst, int* __restrict__ counts) {
  int e = blockIdx.x * blockDim.x + threadIdx.x;
  if (e < N_EDGES) atomicAdd(&counts[dst[e]], 1);
}

__global__ void scan_excl(const int* __restrict__ counts, int* __restrict__ row_ptr,
                          int* __restrict__ cursor) {
  __shared__ int buf[1024];
  const int tid = threadIdx.x;
  int carry = 0;
  for (int base = 0; base < N_NODES; base += 1024) {
    int idx = base + tid;
    int v = (idx < N_NODES) ? counts[idx] : 0;
    buf[tid] = v;
    __syncthreads();
    int sum = v;
    for (int off = 1; off < 1024; off <<= 1) {
      int add = (tid >= off) ? buf[tid - off] : 0;
      __syncthreads();
      sum += add;
      buf[tid] = sum;
      __syncthreads();
    }
    if (idx < N_NODES) {
      int excl = carry + sum - v;
      row_ptr[idx] = excl;
      cursor[idx] = excl;
    }
    carry += buf[1023];
    __syncthreads();
  }
  if (tid == 0) row_ptr[N_NODES] = carry;
}

__global__ void scatter_edges(const int* __restrict__ src, const int* __restrict__ dst,
                              int* __restrict__ cursor, int* __restrict__ esrc) {
  int e = blockIdx.x * blockDim.x + threadIdx.x;
  if (e < N_EDGES) {
    int d = dst[e];
    int pos = atomicAdd(&cursor[d], 1);
    esrc[pos] = src[e];
  }
}

// ---------------- segment max over bf16 h (node-centric, CSR) ----------------
// one block per node; 128 threads x ushort4 (4 feats, 8B) = 512 features
__global__ __launch_bounds__(128) void seg_max(const bf16r* __restrict__ h,
                                               const int* __restrict__ row_ptr,
                                               const int* __restrict__ esrc,
                                               bf16r* __restrict__ hN) {
  const int node = blockIdx.x;
  const int t = threadIdx.x;
  const int beg = row_ptr[node];
  const int end = row_ptr[node + 1];
  float m0 = -INFINITY, m1 = -INFINITY, m2 = -INFINITY, m3 = -INFINITY;
  __shared__ int se[64];
  for (int cb = beg; cb < end; cb += 64) {
    int c = min(64, end - cb);
    __syncthreads();
    if (t < c) se[t] = esrc[cb + t];
    __syncthreads();
    for (int i = 0; i < c; ++i) {
      ushort4 u = reinterpret_cast<const ushort4*>(h + (size_t)se[i] * DIM_P)[t];
      m0 = fmaxf(m0, b2f(u.x));
      m1 = fmaxf(m1, b2f(u.y));
      m2 = fmaxf(m2, b2f(u.z));
      m3 = fmaxf(m3, b2f(u.w));
    }
  }
  if (beg == end) { m0 = 0.f; m1 = 0.f; m2 = 0.f; m3 = 0.f; }
  ushort4 o;
  o.x = f2b(m0); o.y = f2b(m1); o.z = f2b(m2); o.w = f2b(m3);
  reinterpret_cast<ushort4*>(hN + (size_t)node * DIM_P)[t] = o;
}

// ---------------- fp32-accum tiled GEMM, generic input/output types ----------------
// C[M,NC] = A1[M,K1] @ B[0:K1] (+ A2[M,K2] @ B[K1:K1+K2]) ; optional relu
template <int BN, int TN, bool DUAL, bool RELU, typename TA1, typename TA2, typename TO>
__global__ __launch_bounds__(256) void gemm_fused(
    const TA1* __restrict__ A1, int K1, const TA2* __restrict__ A2, int K2,
    const float* __restrict__ B, TO* __restrict__ C, int M, int NC) {
  constexpr int BM = 128, BK = 16, TM = 8;
  constexpr int PAD = 4;
  __shared__ float As[BK][BM + PAD];
  __shared__ float Bs[BK][BN + PAD];
  const int tid = threadIdx.x;
  const int tx = tid % (BN / TN);
  const int ty = tid / (BN / TN);
  const int m0 = blockIdx.x * BM;
  const int n0 = blockIdx.y * BN;

  float acc[TM][TN];
#pragma unroll
  for (int i = 0; i < TM; ++i)
#pragma unroll
    for (int j = 0; j < TN; ++j) acc[i][j] = 0.f;

  for (int phase = 0; phase < (DUAL ? 2 : 1); ++phase) {
    const int K = phase ? K2 : K1;
    const int kb_off = phase ? K1 : 0;
    for (int kt = 0; kt < K; kt += BK) {
      __syncthreads();
      // stage A tile transposed: As[k][m]
#pragma unroll
      for (int i = 0; i < (BM * BK) / (256 * 4); ++i) {
        int lid = tid + i * 256;
        int row = lid / (BK / 4);
        int c4 = (lid % (BK / 4)) * 4;
        int gr = m0 + row;
        float4 v = make_float4(0.f, 0.f, 0.f, 0.f);
        if (gr < M) {
          if (phase == 0)
            v = ld4(A1 + (size_t)gr * K + kt + c4);
          else
            v = ld4(A2 + (size_t)gr * K + kt + c4);
        }
        As[c4 + 0][row] = v.x;
        As[c4 + 1][row] = v.y;
        As[c4 + 2][row] = v.z;
        As[c4 + 3][row] = v.w;
      }
      // stage B tile: Bs[k][n]
#pragma unroll
      for (int i = 0; i < (BK * BN) / (256 * 4); ++i) {
        int lid = tid + i * 256;
        int kr = lid / (BN / 4);
        int c4 = (lid % (BN / 4)) * 4;
        float4 v = *reinterpret_cast<const float4*>(
            B + (size_t)(kb_off + kt + kr) * NC + n0 + c4);
        *reinterpret_cast<float4*>(&Bs[kr][c4]) = v;
      }
      __syncthreads();
#pragma unroll
      for (int kk = 0; kk < BK; ++kk) {
        float a[TM], b[TN];
#pragma unroll
        for (int i = 0; i < TM; i += 4)
          *reinterpret_cast<float4*>(&a[i]) =
              *reinterpret_cast<const float4*>(&As[kk][ty * TM + i]);
#pragma unroll
        for (int j = 0; j < TN; j += 4)
          *reinterpret_cast<float4*>(&b[j]) =
              *reinterpret_cast<const float4*>(&Bs[kk][tx * TN + j]);
#pragma unroll
        for (int i = 0; i < TM; ++i)
#pragma unroll
          for (int j = 0; j < TN; ++j) acc[i][j] = fmaf(a[i], b[j], acc[i][j]);
      }
    }
  }
  // writeback
#pragma unroll
  for (int i = 0; i < TM; ++i) {
    int gr = m0 + ty * TM + i;
    if (gr < M) {
#pragma unroll
      for (int j = 0; j < TN; j += 4) {
        float4 v;
        v.x = acc[i][j + 0];
        v.y = acc[i][j + 1];
        v.z = acc[i][j + 2];
        v.w = acc[i][j + 3];
        if (RELU) {
          v.x = fmaxf(v.x, 0.f);
          v.y = fmaxf(v.y, 0.f);
          v.z = fmaxf(v.z, 0.f);
          v.w = fmaxf(v.w, 0.f);
        }
        st4(C + (size_t)gr * NC + n0 + tx * TN + j, v);
      }
    }
  }
}

// ---------------- full network ----------------
template <typename ActT>
static void run_net(const float* x, const int* src, const int* dst,
                    const float* aggW0, const float* aggW1, const float* aggW2,
                    const float* linW0, const float* linW1, const float* linW2,
                    float* out, char* ws, hipStream_t stream) {
  size_t off = 0;
  auto alloc = [&](size_t bytes) {
    void* p = ws + off;
    off = (off + bytes + 511) & ~(size_t)511;
    return p;
  };
  bf16r* h = (bf16r*)alloc((size_t)N_NODES * DIM_P * 2);   // 51.2 MB
  bf16r* hN = (bf16r*)alloc((size_t)N_NODES * DIM_P * 2);  // 51.2 MB
  ActT* act1 = (ActT*)alloc((size_t)N_NODES * DIM_H * sizeof(ActT));
  ActT* act2 = (ActT*)alloc((size_t)N_NODES * DIM_H * sizeof(ActT));
  int* row_ptr = (int*)alloc((N_NODES + 1) * 4);
  int* cursor = (int*)alloc(N_NODES * 4);
  int* counts = (int*)alloc(N_NODES * 4);
  int* esrc = (int*)alloc(N_EDGES * 4);

  // ---- CSR build (same edges for all 3 layers) ----
  zero_ints<<<(N_NODES + 255) / 256, 256, 0, stream>>>(counts, N_NODES);
  count_edges<<<(N_EDGES + 255) / 256, 256, 0, stream>>>(dst, counts);
  scan_excl<<<1, 1024, 0, stream>>>(counts, row_ptr, cursor);
  scatter_edges<<<(N_EDGES + 255) / 256, 256, 0, stream>>>(src, dst, cursor, esrc);

  dim3 grid_agg((N_NODES + 127) / 128, DIM_P / 128);
  dim3 grid_lin((N_NODES + 127) / 128, DIM_H / 128);
  dim3 grid_out((N_NODES + 127) / 128, DIM_O / 64);

  // ---- layer 0 ----
  gemm_fused<128, 8, false, false><<<grid_agg, 256, 0, stream>>>(
      x, DIM_D, (const bf16r*)nullptr, 0, aggW0, h, N_NODES, DIM_P);
  seg_max<<<N_NODES, 128, 0, stream>>>(h, row_ptr, esrc, hN);
  gemm_fused<128, 8, true, true><<<grid_lin, 256, 0, stream>>>(
      x, DIM_D, hN, DIM_P, linW0, act1, N_NODES, DIM_H);

  // ---- layer 1 ----
  gemm_fused<128, 8, false, false><<<grid_agg, 256, 0, stream>>>(
      act1, DIM_H, (const bf16r*)nullptr, 0, aggW1, h, N_NODES, DIM_P);
  seg_max<<<N_NODES, 128, 0, stream>>>(h, row_ptr, esrc, hN);
  gemm_fused<128, 8, true, true><<<grid_lin, 256, 0, stream>>>(
      act1, DIM_H, hN, DIM_P, linW1, act2, N_NODES, DIM_H);

  // ---- layer 2 (output, no relu) ----
  gemm_fused<128, 8, false, false><<<grid_agg, 256, 0, stream>>>(
      act2, DIM_H, (const bf16r*)nullptr, 0, aggW2, h, N_NODES, DIM_P);
  seg_max<<<N_NODES, 128, 0, stream>>>(h, row_ptr, esrc, hN);
  gemm_fused<64, 4, true, false><<<grid_out, 256, 0, stream>>>(
      act2, DIM_H, hN, DIM_P, linW2, out, N_NODES, DIM_O);
}

extern "C" void kernel_launch(void* const* d_in, const int* in_sizes, int n_in,
                              void* d_out, int out_size, void* d_ws, size_t ws_size,
                              hipStream_t stream) {
  const float* x = (const float*)d_in[0];
  const int* src = (const int*)d_in[1];
  const int* dst = (const int*)d_in[2];
  const float* aggW0 = (const float*)d_in[3];
  const float* aggW1 = (const float*)d_in[4];
  const float* aggW2 = (const float*)d_in[5];
  const float* linW0 = (const float*)d_in[6];
  const float* linW1 = (const float*)d_in[7];
  const float* linW2 = (const float*)d_in[8];
  float* out = (float*)d_out;

  // required bytes: h(51.2M) + hN(51.2M) + 2*act + CSR(~3.8M) + padding
  const size_t need_f32_acts =
      (size_t)N_NODES * DIM_P * 2 * 2 + (size_t)N_NODES * DIM_H * 4 * 2 +
      (size_t)(N_NODES * 3 + N_EDGES + 1) * 4 + 8192;
  if (ws_size >= need_f32_acts) {
    run_net<float>(x, src, dst, aggW0, aggW1, aggW2, linW0, linW1, linW2, out,
                   (char*)d_ws, stream);
  } else {
    run_net<bf16r>(x, src, dst, aggW0, aggW1, aggW2, linW0, linW1, linW2, out,
                   (char*)d_ws, stream);
  }
}

// Round 3
// 805.813 us; speedup vs baseline: 2.0722x; 2.0722x over previous
//
#include <hip/hip_runtime.h>
#include <hip/hip_bf16.h>

#define MN 50000
#define NE 800000
#define DD 128
#define HH 256
#define PP 512
#define OO 64

typedef unsigned short bf16r;  // raw bf16 bits
using short8 = __attribute__((ext_vector_type(8))) short;
using f32x4 = __attribute__((ext_vector_type(4))) float;

__device__ __forceinline__ float b2f(bf16r s) {
  unsigned int u = ((unsigned int)s) << 16;
  float f;
  __builtin_memcpy(&f, &u, 4);
  return f;
}
__device__ __forceinline__ bf16r f2b(float f) {
  unsigned int u;
  __builtin_memcpy(&u, &f, 4);
  u += 0x7fffu + ((u >> 16) & 1u);  // RNE
  return (bf16r)(u >> 16);
}
__device__ __forceinline__ void stC(float* p, float v) { *p = v; }
__device__ __forceinline__ void stC(bf16r* p, float v) { *p = f2b(v); }

// async global->LDS 16B; LDS dest must be wave-uniform-base + lane*16
__device__ __forceinline__ void async16(void* lds, const void* g) {
  auto l = reinterpret_cast<__attribute__((address_space(3))) char*>(
      reinterpret_cast<uintptr_t>(lds));
  auto gp = reinterpret_cast<const __attribute__((address_space(1))) char*>(
      reinterpret_cast<uintptr_t>(g));
  __builtin_amdgcn_global_load_lds(gp, l, 16, 0, 0);
}

// ---------------- small utility ----------------
__global__ void zero_ints(int* __restrict__ p, int n) {
  int i = blockIdx.x * blockDim.x + threadIdx.x;
  if (i < n) p[i] = 0;
}

// transpose + convert weights: B[K][Nc] fp32 -> BT[Nc][K] bf16
__global__ void transpose_w(const float* __restrict__ B, bf16r* __restrict__ BT,
                            int K, int Nc) {
  int idx = blockIdx.x * 256 + threadIdx.x;
  if (idx < K * Nc) {
    int k = idx / Nc, n = idx - k * Nc;
    BT[(size_t)n * K + k] = f2b(B[idx]);
  }
}

// ---------------- CSR build (by dst) ----------------
__global__ void count_edges(const int* __restrict__ dst, int* __restrict__ counts) {
  int e = blockIdx.x * blockDim.x + threadIdx.x;
  if (e < NE) atomicAdd(&counts[dst[e]], 1);
}

__global__ void scan_excl(const int* __restrict__ counts, int* __restrict__ row_ptr,
                          int* __restrict__ cursor) {
  __shared__ int buf[1024];
  const int tid = threadIdx.x;
  int carry = 0;
  for (int base = 0; base < MN; base += 1024) {
    int idx = base + tid;
    int v = (idx < MN) ? counts[idx] : 0;
    buf[tid] = v;
    __syncthreads();
    int sum = v;
    for (int off = 1; off < 1024; off <<= 1) {
      int add = (tid >= off) ? buf[tid - off] : 0;
      __syncthreads();
      sum += add;
      buf[tid] = sum;
      __syncthreads();
    }
    if (idx < MN) {
      int excl = carry + sum - v;
      row_ptr[idx] = excl;
      cursor[idx] = excl;
    }
    carry += buf[1023];
    __syncthreads();
  }
  if (tid == 0) row_ptr[MN] = carry;
}

__global__ void scatter_edges(const int* __restrict__ src, const int* __restrict__ dst,
                              int* __restrict__ cursor, int* __restrict__ esrc) {
  int e = blockIdx.x * blockDim.x + threadIdx.x;
  if (e < NE) {
    int d = dst[e];
    int pos = atomicAdd(&cursor[d], 1);
    esrc[pos] = src[e];
  }
}

// ---------------- segment max over bf16 h (node-centric, CSR) ----------------
__global__ __launch_bounds__(128) void seg_max(const bf16r* __restrict__ h,
                                               const int* __restrict__ row_ptr,
                                               const int* __restrict__ esrc,
                                               bf16r* __restrict__ hN) {
  const int node = blockIdx.x;
  const int t = threadIdx.x;
  const int beg = row_ptr[node];
  const int end = row_ptr[node + 1];
  float m0 = -INFINITY, m1 = -INFINITY, m2 = -INFINITY, m3 = -INFINITY;
  __shared__ int se[64];
  for (int cb = beg; cb < end; cb += 64) {
    int c = min(64, end - cb);
    __syncthreads();
    if (t < c) se[t] = esrc[cb + t];
    __syncthreads();
    for (int i = 0; i < c; ++i) {
      ushort4 u = reinterpret_cast<const ushort4*>(h + (size_t)se[i] * PP)[t];
      m0 = fmaxf(m0, b2f(u.x));
      m1 = fmaxf(m1, b2f(u.y));
      m2 = fmaxf(m2, b2f(u.z));
      m3 = fmaxf(m3, b2f(u.w));
    }
  }
  if (beg == end) { m0 = 0.f; m1 = 0.f; m2 = 0.f; m3 = 0.f; }
  ushort4 o;
  o.x = f2b(m0); o.y = f2b(m1); o.z = f2b(m2); o.w = f2b(m3);
  reinterpret_cast<ushort4*>(hN + (size_t)node * PP)[t] = o;
}

// ---------------- bf16 MFMA GEMM (m97-style 128xBN tile, BK=32) ----------------
// C[M,NC] = A1[M,K1] @ BT[0:NC][0:K1]^T  (+ A2[M,K2] @ BT[][K1:K1+K2]^T); opt relu
// BT is [NC][Ktot] row-major bf16 (pre-transposed weights).
// A operands are bf16 in ws (OOB tail rows of last block read adjacent ws — safe),
// except layer-0's A1 which is fp32 x, reg-staged + converted (A1F32=true).
template <int BN, int WMC, int WNC, bool DUAL, bool RELU, bool A1F32, typename TO>
__global__ __launch_bounds__(256) void gemm_mfma(
    const void* __restrict__ A1v, int K1, const bf16r* __restrict__ A2, int K2,
    const bf16r* __restrict__ BT, int Ktot, TO* __restrict__ C, int M, int NC) {
  constexpr int BM = 128, BK = 32;
  constexpr int WM = BM / WMC;
  constexpr int WN = BN / WNC;
  constexpr int FM = WM / 16, FN = WN / 16;
  __shared__ short As[BM * BK];
  __shared__ short Bs[BN * BK];
  const int tid = threadIdx.x;
  const int lane = tid & 63;
  const int wv = tid >> 6;
  const int wr = wv / WNC, wc = wv % WNC;
  const int m0 = blockIdx.x * BM;
  const int n0 = blockIdx.y * BN;

  f32x4 acc[FM][FN];
#pragma unroll
  for (int i = 0; i < FM; ++i)
#pragma unroll
    for (int j = 0; j < FN; ++j)
#pragma unroll
      for (int r = 0; r < 4; ++r) acc[i][j][r] = 0.f;

#pragma unroll
  for (int ph = 0; ph < (DUAL ? 2 : 1); ++ph) {
    const int K = ph ? K2 : K1;
    const int kb = ph ? K1 : 0;
    const bf16r* Ab = ph ? A2 : (const bf16r*)A1v;
    const float* Af = (const float*)A1v;
    for (int kt = 0; kt < K; kt += BK) {
      __syncthreads();
      if (A1F32 && ph == 0) {
        // reg-stage fp32 x -> bf16 LDS; clamp row (x has exactly M rows)
        const int row = tid >> 1;
        const int cb = (tid & 1) * 16;
        const int gr = min(m0 + row, M - 1);
        const float* gp = Af + (size_t)gr * K + kt + cb;
        float4 v0 = *(const float4*)gp;
        float4 v1 = *(const float4*)(gp + 4);
        float4 v2 = *(const float4*)(gp + 8);
        float4 v3 = *(const float4*)(gp + 12);
        short8 s0, s1;
        s0[0] = (short)f2b(v0.x); s0[1] = (short)f2b(v0.y);
        s0[2] = (short)f2b(v0.z); s0[3] = (short)f2b(v0.w);
        s0[4] = (short)f2b(v1.x); s0[5] = (short)f2b(v1.y);
        s0[6] = (short)f2b(v1.z); s0[7] = (short)f2b(v1.w);
        s1[0] = (short)f2b(v2.x); s1[1] = (short)f2b(v2.y);
        s1[2] = (short)f2b(v2.z); s1[3] = (short)f2b(v2.w);
        s1[4] = (short)f2b(v3.x); s1[5] = (short)f2b(v3.y);
        s1[6] = (short)f2b(v3.z); s1[7] = (short)f2b(v3.w);
        *(short8*)(As + row * BK + cb) = s0;
        *(short8*)(As + row * BK + cb + 8) = s1;
      } else {
        // async stage A tile [128][32] bf16 = 8192 B (2 chunks of 4096)
        const int o = wv * 1024 + lane * 16;
#pragma unroll
        for (int c = 0; c < 2; ++c) {
          int oo = o + c * 4096;
          int row = oo >> 6, colb = oo & 63;
          const char* g = (const char*)Ab + ((size_t)(m0 + row) * K + kt) * 2 + colb;
          async16((char*)As + oo, g);
        }
      }
      {
        // async stage BT tile [BN][32] bf16
        const int o = wv * 1024 + lane * 16;
#pragma unroll
        for (int c = 0; c < (BN * 64) / 4096; ++c) {
          int oo = o + c * 4096;
          int row = oo >> 6, colb = oo & 63;
          const char* g =
              (const char*)BT + ((size_t)(n0 + row) * Ktot + kb + kt) * 2 + colb;
          async16((char*)Bs + oo, g);
        }
      }
      __syncthreads();
      short8 af[FM], bfv[FN];
#pragma unroll
      for (int i = 0; i < FM; ++i)
        af[i] = *(const short8*)(As + (wr * WM + i * 16 + (lane & 15)) * BK +
                                 (lane >> 4) * 8);
#pragma unroll
      for (int j = 0; j < FN; ++j)
        bfv[j] = *(const short8*)(Bs + (wc * WN + j * 16 + (lane & 15)) * BK +
                                  (lane >> 4) * 8);
#pragma unroll
      for (int i = 0; i < FM; ++i)
#pragma unroll
        for (int j = 0; j < FN; ++j)
          acc[i][j] =
              __builtin_amdgcn_mfma_f32_16x16x32_bf16(af[i], bfv[j], acc[i][j], 0, 0, 0);
    }
  }
  // epilogue: C/D layout col=lane&15, row=(lane>>4)*4+r
  const int crow0 = wr * WM + (lane >> 4) * 4;
  const int ccol0 = wc * WN + (lane & 15);
#pragma unroll
  for (int i = 0; i < FM; ++i)
#pragma unroll
    for (int j = 0; j < FN; ++j)
#pragma unroll
      for (int r = 0; r < 4; ++r) {
        int row = m0 + crow0 + i * 16 + r;
        if (row < M) {
          float v = acc[i][j][r];
          if (RELU) v = fmaxf(v, 0.f);
          stC(&C[(size_t)row * NC + n0 + ccol0 + j * 16], v);
        }
      }
}

extern "C" void kernel_launch(void* const* d_in, const int* in_sizes, int n_in,
                              void* d_out, int out_size, void* d_ws, size_t ws_size,
                              hipStream_t stream) {
  const float* x = (const float*)d_in[0];
  const int* src = (const int*)d_in[1];
  const int* dst = (const int*)d_in[2];
  const float* aggW0 = (const float*)d_in[3];
  const float* aggW1 = (const float*)d_in[4];
  const float* aggW2 = (const float*)d_in[5];
  const float* linW0 = (const float*)d_in[6];
  const float* linW1 = (const float*)d_in[7];
  const float* linW2 = (const float*)d_in[8];
  float* out = (float*)d_out;

  char* ws = (char*)d_ws;
  size_t off = 0;
  auto alloc = [&](size_t bytes) {
    void* p = ws + off;
    off = (off + bytes + 255) & ~(size_t)255;
    return p;
  };
  // order matters: GEMM A-staging overreads last-block tail rows into the NEXT buffer
  bf16r* h = (bf16r*)alloc((size_t)MN * PP * 2);      // 51.2 MB
  bf16r* hN = (bf16r*)alloc((size_t)MN * PP * 2);     // 51.2 MB
  bf16r* act1 = (bf16r*)alloc((size_t)MN * HH * 2);   // 25.6 MB
  bf16r* act2 = (bf16r*)alloc((size_t)MN * HH * 2);   // 25.6 MB
  bf16r* aggW0T = (bf16r*)alloc(512 * 128 * 2);
  bf16r* aggW1T = (bf16r*)alloc(512 * 256 * 2);
  bf16r* aggW2T = (bf16r*)alloc(512 * 256 * 2);
  bf16r* linW0T = (bf16r*)alloc(640 * 256 * 2);
  bf16r* linW1T = (bf16r*)alloc(768 * 256 * 2);
  bf16r* linW2T = (bf16r*)alloc(768 * 64 * 2);
  int* row_ptr = (int*)alloc((MN + 1) * 4);
  int* cursor = (int*)alloc(MN * 4);
  int* counts = (int*)alloc(MN * 4);
  int* esrc = (int*)alloc(NE * 4);

  // ---- CSR build ----
  zero_ints<<<(MN + 255) / 256, 256, 0, stream>>>(counts, MN);
  count_edges<<<(NE + 255) / 256, 256, 0, stream>>>(dst, counts);
  scan_excl<<<1, 1024, 0, stream>>>(counts, row_ptr, cursor);
  scatter_edges<<<(NE + 255) / 256, 256, 0, stream>>>(src, dst, cursor, esrc);

  // ---- weight transpose+bf16 ----
  transpose_w<<<(128 * 512 + 255) / 256, 256, 0, stream>>>(aggW0, aggW0T, 128, 512);
  transpose_w<<<(256 * 512 + 255) / 256, 256, 0, stream>>>(aggW1, aggW1T, 256, 512);
  transpose_w<<<(256 * 512 + 255) / 256, 256, 0, stream>>>(aggW2, aggW2T, 256, 512);
  transpose_w<<<(640 * 256 + 255) / 256, 256, 0, stream>>>(linW0, linW0T, 640, 256);
  transpose_w<<<(768 * 256 + 255) / 256, 256, 0, stream>>>(linW1, linW1T, 768, 256);
  transpose_w<<<(768 * 64 + 255) / 256, 256, 0, stream>>>(linW2, linW2T, 768, 64);

  dim3 g512((MN + 127) / 128, 4);
  dim3 g256((MN + 127) / 128, 2);
  dim3 g64((MN + 127) / 128, 1);

  // ---- layer 0 ----
  gemm_mfma<128, 2, 2, false, false, true, bf16r><<<g512, 256, 0, stream>>>(
      x, DD, (const bf16r*)nullptr, 0, aggW0T, DD, h, MN, PP);
  seg_max<<<MN, 128, 0, stream>>>(h, row_ptr, esrc, hN);
  gemm_mfma<128, 2, 2, true, true, true, bf16r><<<g256, 256, 0, stream>>>(
      x, DD, hN, PP, linW0T, DD + PP, act1, MN, HH);

  // ---- layer 1 ----
  gemm_mfma<128, 2, 2, false, false, false, bf16r><<<g512, 256, 0, stream>>>(
      act1, HH, (const bf16r*)nullptr, 0, aggW1T, HH, h, MN, PP);
  seg_max<<<MN, 128, 0, stream>>>(h, row_ptr, esrc, hN);
  gemm_mfma<128, 2, 2, true, true, false, bf16r><<<g256, 256, 0, stream>>>(
      act1, HH, hN, PP, linW1T, HH + PP, act2, MN, HH);

  // ---- layer 2 (output) ----
  gemm_mfma<128, 2, 2, false, false, false, bf16r><<<g512, 256, 0, stream>>>(
      act2, HH, (const bf16r*)nullptr, 0, aggW2T, HH, h, MN, PP);
  seg_max<<<MN, 128, 0, stream>>>(h, row_ptr, esrc, hN);
  gemm_mfma<64, 4, 1, true, false, false, float><<<g64, 256, 0, stream>>>(
      act2, HH, hN, PP, linW2T, HH + PP, out, MN, OO);
}

// Round 4
// 805.083 us; speedup vs baseline: 2.0741x; 1.0009x over previous
//
#include <hip/hip_runtime.h>
#include <hip/hip_bf16.h>

#define MN 50000
#define NE 800000
#define DD 128
#define HH 256
#define PP 512
#define OO 64

typedef unsigned short bf16r;  // raw bf16 bits
using short8 = __attribute__((ext_vector_type(8))) short;
using ushort8 = __attribute__((ext_vector_type(8))) unsigned short;
using f32x4 = __attribute__((ext_vector_type(4))) float;

__device__ __forceinline__ float b2f(bf16r s) {
  unsigned int u = ((unsigned int)s) << 16;
  float f;
  __builtin_memcpy(&f, &u, 4);
  return f;
}
__device__ __forceinline__ bf16r f2b(float f) {
  unsigned int u;
  __builtin_memcpy(&u, &f, 4);
  u += 0x7fffu + ((u >> 16) & 1u);  // RNE
  return (bf16r)(u >> 16);
}
__device__ __forceinline__ void stC(float* p, float v) { *p = v; }
__device__ __forceinline__ void stC(bf16r* p, float v) { *p = f2b(v); }

// async global->LDS 16B; LDS dest must be wave-uniform-base + lane*16
__device__ __forceinline__ void async16(void* lds, const void* g) {
  auto l = reinterpret_cast<__attribute__((address_space(3))) char*>(
      reinterpret_cast<uintptr_t>(lds));
  auto gp = reinterpret_cast<const __attribute__((address_space(1))) char*>(
      reinterpret_cast<uintptr_t>(g));
  __builtin_amdgcn_global_load_lds(gp, l, 16, 0, 0);
}

// ---------------- small utility ----------------
__global__ void zero_ints(int* __restrict__ p, int n) {
  int i = blockIdx.x * blockDim.x + threadIdx.x;
  if (i < n) p[i] = 0;
}

// fp32 -> bf16 vectorized convert (4 elems/thread)
__global__ void conv_bf16(const float* __restrict__ in, bf16r* __restrict__ out, int n4) {
  int i = blockIdx.x * 256 + threadIdx.x;
  if (i < n4) {
    float4 v = reinterpret_cast<const float4*>(in)[i];
    ushort4 u;
    u.x = f2b(v.x); u.y = f2b(v.y); u.z = f2b(v.z); u.w = f2b(v.w);
    reinterpret_cast<ushort4*>(out)[i] = u;
  }
}

// transpose + convert weights: B[K][Nc] fp32 -> BT[Nc][K] bf16
__global__ void transpose_w(const float* __restrict__ B, bf16r* __restrict__ BT,
                            int K, int Nc) {
  int idx = blockIdx.x * 256 + threadIdx.x;
  if (idx < K * Nc) {
    int k = idx / Nc, n = idx - k * Nc;
    BT[(size_t)n * K + k] = f2b(B[idx]);
  }
}

// ---------------- CSR build (by dst) ----------------
__global__ void count_edges(const int* __restrict__ dst, int* __restrict__ counts) {
  int e = blockIdx.x * blockDim.x + threadIdx.x;
  if (e < NE) atomicAdd(&counts[dst[e]], 1);
}

__global__ void scan_excl(const int* __restrict__ counts, int* __restrict__ row_ptr,
                          int* __restrict__ cursor) {
  __shared__ int buf[1024];
  const int tid = threadIdx.x;
  int carry = 0;
  for (int base = 0; base < MN; base += 1024) {
    int idx = base + tid;
    int v = (idx < MN) ? counts[idx] : 0;
    buf[tid] = v;
    __syncthreads();
    int sum = v;
    for (int off = 1; off < 1024; off <<= 1) {
      int add = (tid >= off) ? buf[tid - off] : 0;
      __syncthreads();
      sum += add;
      buf[tid] = sum;
      __syncthreads();
    }
    if (idx < MN) {
      int excl = carry + sum - v;
      row_ptr[idx] = excl;
      cursor[idx] = excl;
    }
    carry += buf[1023];
    __syncthreads();
  }
  if (tid == 0) row_ptr[MN] = carry;
}

__global__ void scatter_edges(const int* __restrict__ src, const int* __restrict__ dst,
                              int* __restrict__ cursor, int* __restrict__ esrc) {
  int e = blockIdx.x * blockDim.x + threadIdx.x;
  if (e < NE) {
    int d = dst[e];
    int pos = atomicAdd(&cursor[d], 1);
    esrc[pos] = src[e];
  }
}

// ---------------- segment max: one wave per node, 16B loads, no LDS ----------------
__global__ __launch_bounds__(256) void seg_max(const bf16r* __restrict__ h,
                                               const int* __restrict__ row_ptr,
                                               const int* __restrict__ esrc,
                                               bf16r* __restrict__ hN) {
  const int node = blockIdx.x * 4 + (threadIdx.x >> 6);
  if (node >= MN) return;
  const int lane = threadIdx.x & 63;
  const int beg = row_ptr[node];
  const int end = row_ptr[node + 1];
  float m[8];
#pragma unroll
  for (int j = 0; j < 8; ++j) m[j] = -INFINITY;

  for (int cb = beg; cb < end; cb += 64) {
    const int c = min(64, end - cb);
    int e = (lane < c) ? esrc[cb + lane] : 0;
    for (int i = 0; i < c; ++i) {
      int s = __shfl(e, i);
      ushort8 u = *reinterpret_cast<const ushort8*>(h + (size_t)s * PP + lane * 8);
#pragma unroll
      for (int j = 0; j < 8; ++j) m[j] = fmaxf(m[j], b2f((bf16r)u[j]));
    }
  }
  if (beg == end) {
#pragma unroll
    for (int j = 0; j < 8; ++j) m[j] = 0.f;
  }
  ushort8 o;
#pragma unroll
  for (int j = 0; j < 8; ++j) o[j] = f2b(m[j]);
  *reinterpret_cast<ushort8*>(hN + (size_t)node * PP + lane * 8) = o;
}

// ---------------- bf16 MFMA GEMM (m97-style 128xBN tile, BK=32) ----------------
// C[M,NC] = A1[M,K1] @ BT[0:NC][0:K1]^T  (+ A2[M,K2] @ BT[][K1:K1+K2]^T); opt relu
// BT is [NC][Ktot] row-major bf16. A operands bf16 in ws (OOB tail rows of the
// last M-block read adjacent ws buffers — safe, outputs row-guarded).
template <int BN, int WMC, int WNC, bool DUAL, bool RELU, typename TO>
__global__ __launch_bounds__(256) void gemm_mfma(
    const bf16r* __restrict__ A1, int K1, const bf16r* __restrict__ A2, int K2,
    const bf16r* __restrict__ BT, int Ktot, TO* __restrict__ C, int M, int NC) {
  constexpr int BM = 128, BK = 32;
  constexpr int WM = BM / WMC;
  constexpr int WN = BN / WNC;
  constexpr int FM = WM / 16, FN = WN / 16;
  __shared__ short As[BM * BK];
  __shared__ short Bs[BN * BK];
  const int tid = threadIdx.x;
  const int lane = tid & 63;
  const int wv = tid >> 6;
  const int wr = wv / WNC, wc = wv % WNC;
  const int m0 = blockIdx.x * BM;
  const int n0 = blockIdx.y * BN;

  f32x4 acc[FM][FN];
#pragma unroll
  for (int i = 0; i < FM; ++i)
#pragma unroll
    for (int j = 0; j < FN; ++j)
#pragma unroll
      for (int r = 0; r < 4; ++r) acc[i][j][r] = 0.f;

#pragma unroll
  for (int ph = 0; ph < (DUAL ? 2 : 1); ++ph) {
    const int K = ph ? K2 : K1;
    const int kb = ph ? K1 : 0;
    const bf16r* Ab = ph ? A2 : A1;
    for (int kt = 0; kt < K; kt += BK) {
      __syncthreads();
      {
        // async stage A tile [128][32] bf16 = 8192 B (2 chunks of 4096)
        const int o = wv * 1024 + lane * 16;
#pragma unroll
        for (int c = 0; c < 2; ++c) {
          int oo = o + c * 4096;
          int row = oo >> 6, colb = oo & 63;
          const char* g = (const char*)Ab + ((size_t)(m0 + row) * K + kt) * 2 + colb;
          async16((char*)As + oo, g);
        }
      }
      {
        // async stage BT tile [BN][32] bf16
        const int o = wv * 1024 + lane * 16;
#pragma unroll
        for (int c = 0; c < (BN * 64) / 4096; ++c) {
          int oo = o + c * 4096;
          int row = oo >> 6, colb = oo & 63;
          const char* g =
              (const char*)BT + ((size_t)(n0 + row) * Ktot + kb + kt) * 2 + colb;
          async16((char*)Bs + oo, g);
        }
      }
      __syncthreads();
      short8 af[FM], bfv[FN];
#pragma unroll
      for (int i = 0; i < FM; ++i)
        af[i] = *(const short8*)(As + (wr * WM + i * 16 + (lane & 15)) * BK +
                                 (lane >> 4) * 8);
#pragma unroll
      for (int j = 0; j < FN; ++j)
        bfv[j] = *(const short8*)(Bs + (wc * WN + j * 16 + (lane & 15)) * BK +
                                  (lane >> 4) * 8);
#pragma unroll
      for (int i = 0; i < FM; ++i)
#pragma unroll
        for (int j = 0; j < FN; ++j)
          acc[i][j] =
              __builtin_amdgcn_mfma_f32_16x16x32_bf16(af[i], bfv[j], acc[i][j], 0, 0, 0);
    }
  }
  // epilogue: C/D layout col=lane&15, row=(lane>>4)*4+r
  const int crow0 = wr * WM + (lane >> 4) * 4;
  const int ccol0 = wc * WN + (lane & 15);
#pragma unroll
  for (int i = 0; i < FM; ++i)
#pragma unroll
    for (int j = 0; j < FN; ++j)
#pragma unroll
      for (int r = 0; r < 4; ++r) {
        int row = m0 + crow0 + i * 16 + r;
        if (row < M) {
          float v = acc[i][j][r];
          if (RELU) v = fmaxf(v, 0.f);
          stC(&C[(size_t)row * NC + n0 + ccol0 + j * 16], v);
        }
      }
}

extern "C" void kernel_launch(void* const* d_in, const int* in_sizes, int n_in,
                              void* d_out, int out_size, void* d_ws, size_t ws_size,
                              hipStream_t stream) {
  const float* x = (const float*)d_in[0];
  const int* src = (const int*)d_in[1];
  const int* dst = (const int*)d_in[2];
  const float* aggW0 = (const float*)d_in[3];
  const float* aggW1 = (const float*)d_in[4];
  const float* aggW2 = (const float*)d_in[5];
  const float* linW0 = (const float*)d_in[6];
  const float* linW1 = (const float*)d_in[7];
  const float* linW2 = (const float*)d_in[8];
  float* out = (float*)d_out;

  char* ws = (char*)d_ws;
  size_t off = 0;
  auto alloc = [&](size_t bytes) {
    void* p = ws + off;
    off = (off + bytes + 255) & ~(size_t)255;
    return p;
  };
  // order matters: GEMM A-staging overreads last-block tail rows into the NEXT buffer
  bf16r* h = (bf16r*)alloc((size_t)MN * PP * 2);      // 51.2 MB
  bf16r* hN = (bf16r*)alloc((size_t)MN * PP * 2);     // 51.2 MB
  bf16r* act1 = (bf16r*)alloc((size_t)MN * HH * 2);   // 25.6 MB
  bf16r* act2 = (bf16r*)alloc((size_t)MN * HH * 2);   // 25.6 MB
  bf16r* xb = (bf16r*)alloc((size_t)MN * DD * 2);     // 12.8 MB
  bf16r* aggW0T = (bf16r*)alloc(512 * 128 * 2);
  bf16r* aggW1T = (bf16r*)alloc(512 * 256 * 2);
  bf16r* aggW2T = (bf16r*)alloc(512 * 256 * 2);
  bf16r* linW0T = (bf16r*)alloc(640 * 256 * 2);
  bf16r* linW1T = (bf16r*)alloc(768 * 256 * 2);
  bf16r* linW2T = (bf16r*)alloc(768 * 64 * 2);
  int* row_ptr = (int*)alloc((MN + 1) * 4);
  int* cursor = (int*)alloc(MN * 4);
  int* counts = (int*)alloc(MN * 4);
  int* esrc = (int*)alloc(NE * 4);

  // ---- CSR build ----
  zero_ints<<<(MN + 255) / 256, 256, 0, stream>>>(counts, MN);
  count_edges<<<(NE + 255) / 256, 256, 0, stream>>>(dst, counts);
  scan_excl<<<1, 1024, 0, stream>>>(counts, row_ptr, cursor);
  scatter_edges<<<(NE + 255) / 256, 256, 0, stream>>>(src, dst, cursor, esrc);

  // ---- x -> bf16, weight transpose+bf16 ----
  conv_bf16<<<((MN * DD / 4) + 255) / 256, 256, 0, stream>>>(x, xb, MN * DD / 4);
  transpose_w<<<(128 * 512 + 255) / 256, 256, 0, stream>>>(aggW0, aggW0T, 128, 512);
  transpose_w<<<(256 * 512 + 255) / 256, 256, 0, stream>>>(aggW1, aggW1T, 256, 512);
  transpose_w<<<(256 * 512 + 255) / 256, 256, 0, stream>>>(aggW2, aggW2T, 256, 512);
  transpose_w<<<(640 * 256 + 255) / 256, 256, 0, stream>>>(linW0, linW0T, 640, 256);
  transpose_w<<<(768 * 256 + 255) / 256, 256, 0, stream>>>(linW1, linW1T, 768, 256);
  transpose_w<<<(768 * 64 + 255) / 256, 256, 0, stream>>>(linW2, linW2T, 768, 64);

  dim3 g512((MN + 127) / 128, 4);
  dim3 g256((MN + 127) / 128, 2);
  dim3 g64((MN + 127) / 128, 1);
  const int segGrid = (MN + 3) / 4;

  // ---- layer 0 ----
  gemm_mfma<128, 2, 2, false, false, bf16r><<<g512, 256, 0, stream>>>(
      xb, DD, (const bf16r*)nullptr, 0, aggW0T, DD, h, MN, PP);
  seg_max<<<segGrid, 256, 0, stream>>>(h, row_ptr, esrc, hN);
  gemm_mfma<128, 2, 2, true, true, bf16r><<<g256, 256, 0, stream>>>(
      xb, DD, hN, PP, linW0T, DD + PP, act1, MN, HH);

  // ---- layer 1 ----
  gemm_mfma<128, 2, 2, false, false, bf16r><<<g512, 256, 0, stream>>>(
      act1, HH, (const bf16r*)nullptr, 0, aggW1T, HH, h, MN, PP);
  seg_max<<<segGrid, 256, 0, stream>>>(h, row_ptr, esrc, hN);
  gemm_mfma<128, 2, 2, true, true, bf16r><<<g256, 256, 0, stream>>>(
      act1, HH, hN, PP, linW1T, HH + PP, act2, MN, HH);

  // ---- layer 2 (output) ----
  gemm_mfma<128, 2, 2, false, false, bf16r><<<g512, 256, 0, stream>>>(
      act2, HH, (const bf16r*)nullptr, 0, aggW2T, HH, h, MN, PP);
  seg_max<<<segGrid, 256, 0, stream>>>(h, row_ptr, esrc, hN);
  gemm_mfma<64, 4, 1, true, false, float><<<g64, 256, 0, stream>>>(
      act2, HH, hN, PP, linW2T, HH + PP, out, MN, OO);
}

// Round 5
// 742.426 us; speedup vs baseline: 2.2492x; 1.0844x over previous
//
#include <hip/hip_runtime.h>
#include <hip/hip_bf16.h>

#define MN 50000
#define NE 800000
#define DD 128
#define HH 256
#define PP 512
#define OO 64

typedef unsigned short bf16r;  // raw bf16 bits
using short8 = __attribute__((ext_vector_type(8))) short;
using ushort8 = __attribute__((ext_vector_type(8))) unsigned short;
using f32x4 = __attribute__((ext_vector_type(4))) float;

__device__ __forceinline__ float b2f(bf16r s) {
  unsigned int u = ((unsigned int)s) << 16;
  float f;
  __builtin_memcpy(&f, &u, 4);
  return f;
}
__device__ __forceinline__ bf16r f2b(float f) {
  unsigned int u;
  __builtin_memcpy(&u, &f, 4);
  u += 0x7fffu + ((u >> 16) & 1u);  // RNE
  return (bf16r)(u >> 16);
}
// order-preserving involution bf16 bits <-> signed-int16 sortable key
__device__ __forceinline__ unsigned short keymap(unsigned short u) {
  return u ^ ((u & 0x8000u) ? 0x7FFFu : 0u);
}
__device__ __forceinline__ void stC(float* p, float v) { *p = v; }
__device__ __forceinline__ void stC(bf16r* p, float v) { *p = f2b(v); }

// async global->LDS 16B; LDS dest must be wave-uniform-base + lane*16
__device__ __forceinline__ void async16(void* lds, const void* g) {
  auto l = reinterpret_cast<__attribute__((address_space(3))) char*>(
      reinterpret_cast<uintptr_t>(lds));
  auto gp = reinterpret_cast<const __attribute__((address_space(1))) char*>(
      reinterpret_cast<uintptr_t>(g));
  __builtin_amdgcn_global_load_lds(gp, l, 16, 0, 0);
}

// ---------------- small utility ----------------
__global__ void zero_ints(int* __restrict__ p, int n) {
  int i = blockIdx.x * blockDim.x + threadIdx.x;
  if (i < n) p[i] = 0;
}

// fp32 -> bf16 vectorized convert (4 elems/thread)
__global__ void conv_bf16(const float* __restrict__ in, bf16r* __restrict__ out, int n4) {
  int i = blockIdx.x * 256 + threadIdx.x;
  if (i < n4) {
    float4 v = reinterpret_cast<const float4*>(in)[i];
    ushort4 u;
    u.x = f2b(v.x); u.y = f2b(v.y); u.z = f2b(v.z); u.w = f2b(v.w);
    reinterpret_cast<ushort4*>(out)[i] = u;
  }
}

// all 6 weight transposes in one kernel: B[K][Nc] fp32 -> BT[Nc][K] bf16
__device__ __forceinline__ void tw1(const float* B, bf16r* BT, int i, int K, int Nc) {
  int k = i / Nc, n = i - k * Nc;
  BT[(size_t)n * K + k] = f2b(B[i]);
}
__global__ void transpose_all(const float* __restrict__ b0, const float* __restrict__ b1,
                              const float* __restrict__ b2, const float* __restrict__ b3,
                              const float* __restrict__ b4, const float* __restrict__ b5,
                              bf16r* __restrict__ t0, bf16r* __restrict__ t1,
                              bf16r* __restrict__ t2, bf16r* __restrict__ t3,
                              bf16r* __restrict__ t4, bf16r* __restrict__ t5) {
  int idx = blockIdx.x * 256 + threadIdx.x;
  // cum: 65536, 196608, 327680, 491520, 688128, 737280
  if (idx < 196608) {
    if (idx < 65536) tw1(b0, t0, idx, 128, 512);
    else tw1(b1, t1, idx - 65536, 256, 512);
  } else if (idx < 491520) {
    if (idx < 327680) tw1(b2, t2, idx - 196608, 256, 512);
    else tw1(b3, t3, idx - 327680, 640, 256);
  } else if (idx < 737280) {
    if (idx < 688128) tw1(b4, t4, idx - 491520, 768, 256);
    else tw1(b5, t5, idx - 688128, 768, 64);
  }
}

// ---------------- CSR build (by dst) ----------------
__global__ void count_edges(const int* __restrict__ dst, int* __restrict__ counts) {
  int e = blockIdx.x * blockDim.x + threadIdx.x;
  if (e < NE) atomicAdd(&counts[dst[e]], 1);
}

// 2-level parallel exclusive scan over padded counts (51200 elems, 25 blocks x 2048)
__global__ __launch_bounds__(1024) void scan_local(const int* __restrict__ counts,
                                                   int* __restrict__ row_ptr,
                                                   int* __restrict__ bsum) {
  __shared__ int buf[1024];
  const int b = blockIdx.x, t = threadIdx.x;
  int2 c2 = reinterpret_cast<const int2*>(counts)[b * 1024 + t];
  int tsum = c2.x + c2.y;
  buf[t] = tsum;
  __syncthreads();
  int s = tsum;
  for (int off = 1; off < 1024; off <<= 1) {
    int add = (t >= off) ? buf[t - off] : 0;
    __syncthreads();
    s += add;
    buf[t] = s;
    __syncthreads();
  }
  int excl = s - tsum;
  int2 o;
  o.x = excl;
  o.y = excl + c2.x;
  reinterpret_cast<int2*>(row_ptr)[b * 1024 + t] = o;
  if (t == 1023) bsum[b] = s;
}

__global__ __launch_bounds__(1024) void scan_add(int* __restrict__ row_ptr,
                                                 int* __restrict__ cursor,
                                                 const int* __restrict__ bsum) {
  const int b = blockIdx.x, t = threadIdx.x;
  int off = 0;
  for (int j = 0; j < b; ++j) off += bsum[j];
  int i0 = b * 2048 + 2 * t;
#pragma unroll
  for (int k = 0; k < 2; ++k) {
    int i = i0 + k;
    if (i <= MN) {
      int v = row_ptr[i] + off;
      row_ptr[i] = v;
      if (i < MN) cursor[i] = v;
    }
  }
}

__global__ void scatter_edges(const int* __restrict__ src, const int* __restrict__ dst,
                              int* __restrict__ cursor, int* __restrict__ esrc) {
  int e = blockIdx.x * blockDim.x + threadIdx.x;
  if (e < NE) {
    int d = dst[e];
    int pos = atomicAdd(&cursor[d], 1);
    esrc[pos] = src[e];
  }
}

// ---------------- segment max over KEYED h: packed i16 max, 4-edge MLP ----------------
__global__ __launch_bounds__(256) void seg_max(const bf16r* __restrict__ h,
                                               const int* __restrict__ row_ptr,
                                               const int* __restrict__ esrc,
                                               bf16r* __restrict__ hN) {
  const int node = blockIdx.x * 4 + (threadIdx.x >> 6);
  if (node >= MN) return;
  const int lane = threadIdx.x & 63;
  const int beg = row_ptr[node];
  const int end = row_ptr[node + 1];
  short8 m8;
#pragma unroll
  for (int j = 0; j < 8; ++j) m8[j] = (short)0x807F;  // key(-inf bf16)

  for (int cb = beg; cb < end; cb += 64) {
    const int c = min(64, end - cb);
    int e = esrc[cb + min(lane, c - 1)];
    for (int i = 0; i < c; i += 4) {
      int s0 = __shfl(e, i);
      int s1 = __shfl(e, min(i + 1, c - 1));
      int s2 = __shfl(e, min(i + 2, c - 1));
      int s3 = __shfl(e, min(i + 3, c - 1));
      short8 u0 = *reinterpret_cast<const short8*>(h + ((size_t)s0 << 9) + lane * 8);
      short8 u1 = *reinterpret_cast<const short8*>(h + ((size_t)s1 << 9) + lane * 8);
      short8 u2 = *reinterpret_cast<const short8*>(h + ((size_t)s2 << 9) + lane * 8);
      short8 u3 = *reinterpret_cast<const short8*>(h + ((size_t)s3 << 9) + lane * 8);
      m8 = __builtin_elementwise_max(m8, u0);
      m8 = __builtin_elementwise_max(m8, u1);
      m8 = __builtin_elementwise_max(m8, u2);
      m8 = __builtin_elementwise_max(m8, u3);
    }
  }
  ushort8 o;
  if (beg == end) {
#pragma unroll
    for (int j = 0; j < 8; ++j) o[j] = 0;  // DGL zero-fill
  } else {
#pragma unroll
    for (int j = 0; j < 8; ++j) o[j] = keymap((unsigned short)m8[j]);
  }
  *reinterpret_cast<ushort8*>(hN + (size_t)node * PP + lane * 8) = o;
}

// ---------------- bf16 MFMA GEMM (m97-style 128xBN tile, BK=32) ----------------
// C[M,NC] = A1[M,K1] @ BT^T (+ A2 @ BT[][K1:]^T); optional relu.
// KEYED: store bf16 bits through keymap involution (h feeding seg_max only).
template <int BN, int WMC, int WNC, bool DUAL, bool RELU, bool KEYED, typename TO>
__global__ __launch_bounds__(256) void gemm_mfma(
    const bf16r* __restrict__ A1, int K1, const bf16r* __restrict__ A2, int K2,
    const bf16r* __restrict__ BT, int Ktot, TO* __restrict__ C, int M, int NC) {
  constexpr int BM = 128, BK = 32;
  constexpr int WM = BM / WMC;
  constexpr int WN = BN / WNC;
  constexpr int FM = WM / 16, FN = WN / 16;
  __shared__ short As[BM * BK];
  __shared__ short Bs[BN * BK];
  const int tid = threadIdx.x;
  const int lane = tid & 63;
  const int wv = tid >> 6;
  const int wr = wv / WNC, wc = wv % WNC;
  const int m0 = blockIdx.x * BM;
  const int n0 = blockIdx.y * BN;

  f32x4 acc[FM][FN];
#pragma unroll
  for (int i = 0; i < FM; ++i)
#pragma unroll
    for (int j = 0; j < FN; ++j)
#pragma unroll
      for (int r = 0; r < 4; ++r) acc[i][j][r] = 0.f;

#pragma unroll
  for (int ph = 0; ph < (DUAL ? 2 : 1); ++ph) {
    const int K = ph ? K2 : K1;
    const int kb = ph ? K1 : 0;
    const bf16r* Ab = ph ? A2 : A1;
    for (int kt = 0; kt < K; kt += BK) {
      __syncthreads();
      {
        const int o = wv * 1024 + lane * 16;
#pragma unroll
        for (int c = 0; c < 2; ++c) {
          int oo = o + c * 4096;
          int row = oo >> 6, colb = oo & 63;
          const char* g = (const char*)Ab + ((size_t)(m0 + row) * K + kt) * 2 + colb;
          async16((char*)As + oo, g);
        }
      }
      {
        const int o = wv * 1024 + lane * 16;
#pragma unroll
        for (int c = 0; c < (BN * 64) / 4096; ++c) {
          int oo = o + c * 4096;
          int row = oo >> 6, colb = oo & 63;
          const char* g =
              (const char*)BT + ((size_t)(n0 + row) * Ktot + kb + kt) * 2 + colb;
          async16((char*)Bs + oo, g);
        }
      }
      __syncthreads();
      short8 af[FM], bfv[FN];
#pragma unroll
      for (int i = 0; i < FM; ++i)
        af[i] = *(const short8*)(As + (wr * WM + i * 16 + (lane & 15)) * BK +
                                 (lane >> 4) * 8);
#pragma unroll
      for (int j = 0; j < FN; ++j)
        bfv[j] = *(const short8*)(Bs + (wc * WN + j * 16 + (lane & 15)) * BK +
                                  (lane >> 4) * 8);
#pragma unroll
      for (int i = 0; i < FM; ++i)
#pragma unroll
        for (int j = 0; j < FN; ++j)
          acc[i][j] =
              __builtin_amdgcn_mfma_f32_16x16x32_bf16(af[i], bfv[j], acc[i][j], 0, 0, 0);
    }
  }
  // epilogue: C/D layout col=lane&15, row=(lane>>4)*4+r
  const int crow0 = wr * WM + (lane >> 4) * 4;
  const int ccol0 = wc * WN + (lane & 15);
#pragma unroll
  for (int i = 0; i < FM; ++i)
#pragma unroll
    for (int j = 0; j < FN; ++j)
#pragma unroll
      for (int r = 0; r < 4; ++r) {
        int row = m0 + crow0 + i * 16 + r;
        if (row < M) {
          float v = acc[i][j][r];
          if (RELU) v = fmaxf(v, 0.f);
          TO* p = &C[(size_t)row * NC + n0 + ccol0 + j * 16];
          if (KEYED) {
            *(bf16r*)p = keymap(f2b(v));
          } else {
            stC(p, v);
          }
        }
      }
}

extern "C" void kernel_launch(void* const* d_in, const int* in_sizes, int n_in,
                              void* d_out, int out_size, void* d_ws, size_t ws_size,
                              hipStream_t stream) {
  const float* x = (const float*)d_in[0];
  const int* src = (const int*)d_in[1];
  const int* dst = (const int*)d_in[2];
  const float* aggW0 = (const float*)d_in[3];
  const float* aggW1 = (const float*)d_in[4];
  const float* aggW2 = (const float*)d_in[5];
  const float* linW0 = (const float*)d_in[6];
  const float* linW1 = (const float*)d_in[7];
  const float* linW2 = (const float*)d_in[8];
  float* out = (float*)d_out;

  char* ws = (char*)d_ws;
  size_t off = 0;
  auto alloc = [&](size_t bytes) {
    void* p = ws + off;
    off = (off + bytes + 255) & ~(size_t)255;
    return p;
  };
  // order matters: GEMM A-staging overreads last-block tail rows into the NEXT buffer
  bf16r* h = (bf16r*)alloc((size_t)MN * PP * 2);      // keyed bf16
  bf16r* hN = (bf16r*)alloc((size_t)MN * PP * 2);
  bf16r* act1 = (bf16r*)alloc((size_t)MN * HH * 2);
  bf16r* act2 = (bf16r*)alloc((size_t)MN * HH * 2);
  bf16r* xb = (bf16r*)alloc((size_t)MN * DD * 2);
  bf16r* aggW0T = (bf16r*)alloc(512 * 128 * 2);
  bf16r* aggW1T = (bf16r*)alloc(512 * 256 * 2);
  bf16r* aggW2T = (bf16r*)alloc(512 * 256 * 2);
  bf16r* linW0T = (bf16r*)alloc(640 * 256 * 2);
  bf16r* linW1T = (bf16r*)alloc(768 * 256 * 2);
  bf16r* linW2T = (bf16r*)alloc(768 * 64 * 2);
  int* row_ptr = (int*)alloc(51264 * 4);   // padded for int2 scan
  int* cursor = (int*)alloc(MN * 4);
  int* counts = (int*)alloc(51264 * 4);    // padded, zeroed
  int* bsum = (int*)alloc(32 * 4);
  int* esrc = (int*)alloc(NE * 4);

  // ---- CSR build ----
  zero_ints<<<(51264 + 255) / 256, 256, 0, stream>>>(counts, 51264);
  count_edges<<<(NE + 255) / 256, 256, 0, stream>>>(dst, counts);
  scan_local<<<25, 1024, 0, stream>>>(counts, row_ptr, bsum);
  scan_add<<<25, 1024, 0, stream>>>(row_ptr, cursor, bsum);
  scatter_edges<<<(NE + 255) / 256, 256, 0, stream>>>(src, dst, cursor, esrc);

  // ---- x -> bf16, all weight transposes ----
  conv_bf16<<<((MN * DD / 4) + 255) / 256, 256, 0, stream>>>(x, xb, MN * DD / 4);
  transpose_all<<<(737280 + 255) / 256, 256, 0, stream>>>(
      aggW0, aggW1, aggW2, linW0, linW1, linW2,
      aggW0T, aggW1T, aggW2T, linW0T, linW1T, linW2T);

  dim3 g512((MN + 127) / 128, 4);
  dim3 g256((MN + 127) / 128, 2);
  dim3 g64((MN + 127) / 128, 1);
  const int segGrid = (MN + 3) / 4;

  // ---- layer 0 ----
  gemm_mfma<128, 2, 2, false, false, true, bf16r><<<g512, 256, 0, stream>>>(
      xb, DD, (const bf16r*)nullptr, 0, aggW0T, DD, h, MN, PP);
  seg_max<<<segGrid, 256, 0, stream>>>(h, row_ptr, esrc, hN);
  gemm_mfma<128, 2, 2, true, true, false, bf16r><<<g256, 256, 0, stream>>>(
      xb, DD, hN, PP, linW0T, DD + PP, act1, MN, HH);

  // ---- layer 1 ----
  gemm_mfma<128, 2, 2, false, false, true, bf16r><<<g512, 256, 0, stream>>>(
      act1, HH, (const bf16r*)nullptr, 0, aggW1T, HH, h, MN, PP);
  seg_max<<<segGrid, 256, 0, stream>>>(h, row_ptr, esrc, hN);
  gemm_mfma<128, 2, 2, true, true, false, bf16r><<<g256, 256, 0, stream>>>(
      act1, HH, hN, PP, linW1T, HH + PP, act2, MN, HH);

  // ---- layer 2 (output) ----
  gemm_mfma<128, 2, 2, false, false, true, bf16r><<<g512, 256, 0, stream>>>(
      act2, HH, (const bf16r*)nullptr, 0, aggW2T, HH, h, MN, PP);
  seg_max<<<segGrid, 256, 0, stream>>>(h, row_ptr, esrc, hN);
  gemm_mfma<64, 4, 1, true, false, false, float><<<g64, 256, 0, stream>>>(
      act2, HH, hN, PP, linW2T, HH + PP, out, MN, OO);
}